// Round 20
// baseline (268.727 us; speedup 1.0000x reference)
//
#include <hip/hip_runtime.h>
#include <hip/hip_bf16.h>
#include <cstdint>

#define IN_SZ 50000
#define PADC  50048
#define NM 3
#define N0 40960
#define N1 16384
#define NB 4096
#define HD 256
#define DEG 16
#define E0 (N1*DEG)
#define E1 (NB*DEG)

using short8v = __attribute__((ext_vector_type(8))) short;
using floatx4 = __attribute__((ext_vector_type(4))) float;
typedef unsigned short ushort_t;

__device__ __forceinline__ ushort_t f2bf(float f){
  uint32_t u = __float_as_uint(f);
  uint32_t r = u + 0x7FFFu + ((u>>16)&1u);
  return (ushort_t)(r>>16);
}
__device__ __forceinline__ float bf2f(ushort_t h){
  return __uint_as_float(((uint32_t)h)<<16);
}
__device__ __forceinline__ void gload_lds16(const void* g, void* l){
  __builtin_amdgcn_global_load_lds(
      (const __attribute__((address_space(1))) void*)g,
      (__attribute__((address_space(3))) void*)l, 16, 0, 0);
}

// ---------------- threefry2x32 (JAX-exact) ----------------
__device__ __forceinline__ uint32_t rotl32(uint32_t x, uint32_t d){ return (x<<d)|(x>>(32u-d)); }

__device__ void tf2x32(uint32_t k0, uint32_t k1, uint32_t c0, uint32_t c1,
                       uint32_t& y0, uint32_t& y1)
{
  uint32_t ks2 = k0 ^ k1 ^ 0x1BD11BDAu;
  uint32_t x0 = c0 + k0, x1 = c1 + k1;
#define R4(a,b,c,d) \
  x0+=x1; x1=rotl32(x1,a); x1^=x0; \
  x0+=x1; x1=rotl32(x1,b); x1^=x0; \
  x0+=x1; x1=rotl32(x1,c); x1^=x0; \
  x0+=x1; x1=rotl32(x1,d); x1^=x0;
  R4(13,15,26,6)  x0+=k1;  x1+=ks2+1u;
  R4(17,29,16,24) x0+=ks2; x1+=k0+2u;
  R4(13,15,26,6)  x0+=k0;  x1+=k1+3u;
  R4(17,29,16,24) x0+=k1;  x1+=ks2+4u;
  R4(13,15,26,6)  x0+=ks2; x1+=k0+5u;
#undef R4
  y0=x0; y1=x1;
}

// ---- merged prep: [0,16) interp | [16,144) embW transp | [144,912) split |
//      [912,915) bias | [915,927) watt ----
__global__ __launch_bounds__(256) void prep_k(
    const float* __restrict__ masks, const float* __restrict__ sp,
    float* __restrict__ coef, float* __restrict__ scales_out,
    const float* __restrict__ emb_W, float* __restrict__ wT,
    const float* __restrict__ gat_W, ushort_t* __restrict__ gWhi, ushort_t* __restrict__ gWlo,
    const float* __restrict__ pre_b, const float* __restrict__ gat_att,
    const float* __restrict__ gat_b, float* __restrict__ bsum, float* __restrict__ batt,
    float* __restrict__ watt)
{
  int blk = blockIdx.x;
  int t = threadIdx.x;
  if (blk < 16){
    int b = blk*256 + t;
    float s0=sp[0], s1=sp[1], s2=sp[2];
    float mx = fmaxf(s0,fmaxf(s1,s2));
    float e0=expf(s0-mx), e1=expf(s1-mx), e2=expf(s2-mx);
    float inv = 1.f/(e0+e1+e2);
    float sc[3] = {e0*inv, e1*inv, e2*inv};
    if (b == 0){ scales_out[0]=sc[0]; scales_out[1]=sc[1]; scales_out[2]=sc[2]; }
    uint32_t bits[3];
    uint32_t K0,K1, t0,t1;
    tf2x32(0u,42u,0u,1u,K0,K1);
    for (int i=0;i<3;i++){
      uint32_t idx = (uint32_t)(b*3+i);
      tf2x32(K0,K1,0u,idx,t0,t1);
      bits[i] = (t0 ^ t1) & 1u;
    }
    float mk[3] = {masks[b*3+0], masks[b*3+1], masks[b*3+2]};
    float msum = mk[0]+mk[1]+mk[2];
    float rs = (float)(bits[0]+bits[1]+bits[2]);
    float add = powf(1.f/(1.f+rs), 20.f) + powf(1.f/msum, 20.f);
    float lg[3]; float lmax = -1e30f;
    for (int i=0;i<3;i++){
      float rm = floorf((float)bits[i] + add);
      rm = rm/(rm+1e-10f);
      float mm = mk[i]*rm;
      lg[i] = mm + (1.f-mm)*(-1e10f);
      lmax = fmaxf(lmax, lg[i]);
    }
    float es[3], ssum=0.f;
    for (int i=0;i<3;i++){ es[i]=expf(lg[i]-lmax); ssum+=es[i]; }
    for (int i=0;i<3;i++) coef[b*3+i] = sc[i]*es[i]/ssum;
  } else if (blk < 144){
    int g = (blk-16)*256 + t;
    int j = g >> 8, k = g & 255;
    wT[k*128 + j] = emb_W[g];
  } else if (blk < 912){
    int g = (blk-144)*256 + t;
    float v = gat_W[g];
    ushort_t h = f2bf(v);
    gWhi[g] = h;
    gWlo[g] = f2bf(v - bf2f(h));
  } else if (blk < 915){
    int i = blk - 912, o = t;
    const float* W = gat_W + (size_t)i*HD*HD + (size_t)o*HD;
    const float* b = pre_b + i*HD;
    float s = 0.f;
    for (int k=0;k<HD;k++) s = fmaf(b[k], W[k], s);
    bsum[i*HD + o] = s + gat_b[i*HD + o];
    __shared__ float red[256];
    red[o] = s * gat_att[i*HD + o];
    __syncthreads();
    if (o < 4){
      float p = 0.f;
      for (int j=0;j<64;j++) p += red[o*64 + j];
      batt[i*4 + o] = p;
    }
  } else {
    // watt[i][k][h] = sum_{o' in head h} gat_W[i][h*64+o'][k] * gat_att[i][h*64+o']
    int idx = blk - 915;
    int i = idx >> 2, h = idx & 3;
    int k = t;
    float s = 0.f;
    for (int o=0;o<64;o++){
      int oo = h*64 + o;
      s = fmaf(gat_W[(size_t)i*HD*HD + (size_t)oo*HD + k], gat_att[i*HD + oo], s);
    }
    watt[(size_t)i*1024 + k*4 + h] = s;
  }
}

// ---- transpose v2 (page-local): block = [64 k x 256 c]; 1KB contiguous reads,
// 128B page-local row-quarter writes. alphaG partials per k-quarter -> alphG4.
__global__ __launch_bounds__(256) void transpB_k(
    const float* __restrict__ Wb, const float* __restrict__ watt_b,
    ushort_t* __restrict__ WT_b, float* __restrict__ alphG4_b)
{
  int i = blockIdx.z;
  int kq = blockIdx.y;          // k-quarter 0..3
  int c0 = blockIdx.x * 256;
  const float* W = Wb + (size_t)i*HD*IN_SZ;
  ushort_t* WT = WT_b + (size_t)i*(size_t)PADC*HD;
  float* alphG4 = alphG4_b + (size_t)(i*4 + kq)*(size_t)PADC*4;

  __shared__ uint32_t tile[64*129];   // [k_local][cu] bf16 pairs, +1 pad
  __shared__ float wl[256];           // watt rows kq*64..+64, [k_local][h]
  int t = threadIdx.x;
  wl[t] = watt_b[(size_t)i*1024 + (size_t)kq*256 + t];

  // load: 16 iters; per k-row 64 float4 = 1KB contiguous
#pragma unroll
  for (int it=0; it<16; it++){
    int lin = it*256 + t;
    int kl = lin >> 6, quad = lin & 63;
    int cb = c0 + quad*4;
    if (cb > IN_SZ-4) cb = IN_SZ-4;     // clamp (rows >= IN_SZ unused)
    float4 f = *reinterpret_cast<const float4*>(&W[(size_t)(kq*64+kl)*IN_SZ + cb]);
    tile[kl*129 + quad*2]     = (uint32_t)f2bf(f.x) | ((uint32_t)f2bf(f.y)<<16);
    tile[kl*129 + quad*2 + 1] = (uint32_t)f2bf(f.z) | ((uint32_t)f2bf(f.w)<<16);
  }
  __syncthreads();

  // thread t owns column c0+t: extract 64 k values, pack 32 uints, dot with wl
  int c = c0 + t, half = t & 1, cu = t >> 1;
  float p0=0.f,p1=0.f,p2=0.f,p3=0.f;
  uint32_t ou[32];
#pragma unroll
  for (int j=0;j<32;j++){
    uint32_t ua = tile[(2*j)*129 + cu];
    uint32_t ub = tile[(2*j+1)*129 + cu];
    ushort_t va = half ? (ushort_t)(ua>>16) : (ushort_t)(ua & 0xffffu);
    ushort_t vb = half ? (ushort_t)(ub>>16) : (ushort_t)(ub & 0xffffu);
    ou[j] = (uint32_t)va | ((uint32_t)vb<<16);
    float fa = bf2f(va), fb = bf2f(vb);
    p0 = fmaf(fa, wl[(2*j)*4+0], p0); p1 = fmaf(fa, wl[(2*j)*4+1], p1);
    p2 = fmaf(fa, wl[(2*j)*4+2], p2); p3 = fmaf(fa, wl[(2*j)*4+3], p3);
    p0 = fmaf(fb, wl[(2*j+1)*4+0], p0); p1 = fmaf(fb, wl[(2*j+1)*4+1], p1);
    p2 = fmaf(fb, wl[(2*j+1)*4+2], p2); p3 = fmaf(fb, wl[(2*j+1)*4+3], p3);
  }
  if (c < PADC){
    uint32_t* orow = reinterpret_cast<uint32_t*>(WT + (size_t)c*HD + kq*64);
#pragma unroll
    for (int j=0;j<8;j++){
      uint4 v = make_uint4(ou[4*j], ou[4*j+1], ou[4*j+2], ou[4*j+3]);
      *reinterpret_cast<uint4*>(orow + j*4) = v;
    }
    *reinterpret_cast<float4*>(&alphG4[(size_t)c*4]) = make_float4(p0,p1,p2,p3);
  }
}

// ---- layer-0 message in input space: agg[d] = sum_e aw[e,h] * WT[nid[src_e]] ----
// alpha logit = leaky( sum_kq alphG4[kq][src][h] + batt[h] )
__global__ __launch_bounds__(128) void gat_msg0w(
    const ushort_t* __restrict__ WT_b, const float* __restrict__ alphG4_b,
    const float* __restrict__ batt,
    const int* __restrict__ n_ids, const int* __restrict__ esrc_b,
    ushort_t* __restrict__ agg_b)
{
  int i = blockIdx.y, d = blockIdx.x, t = threadIdx.x;
  const ushort_t* WT = WT_b + (size_t)i*(size_t)PADC*HD;
  const float* alphG4 = alphG4_b + (size_t)(i*4)*(size_t)PADC*4;
  __shared__ int src[16];
  __shared__ float aw[16][4];
  if (t < 16) src[t] = n_ids[(size_t)i*N0 + esrc_b[(size_t)i*E0 + d*16 + t]];
  __syncthreads();
  if (t < 64){
    int e = t&15, h = t>>4;
    size_t so = (size_t)src[e]*4 + h;
    float v = alphG4[so] + alphG4[(size_t)PADC*4 + so]
            + alphG4[(size_t)PADC*8 + so] + alphG4[(size_t)PADC*12 + so];
    v += batt[i*4 + h];
    float l = v > 0.f ? v : 0.2f*v;
    float m = l;
#pragma unroll
    for (int off=1; off<16; off<<=1) m = fmaxf(m, __shfl_xor(m, off, 64));
    float ex = expf(l - m);
    float s = ex;
#pragma unroll
    for (int off=1; off<16; off<<=1) s += __shfl_xor(s, off, 64);
    aw[e][h] = ex / (s + 1e-16f);
  }
  __syncthreads();
  int h = t >> 5;
  float a0=0.f, a1=0.f;
#pragma unroll
  for (int e=0;e<16;e++){
    uint32_t u = *reinterpret_cast<const uint32_t*>(WT + (size_t)src[e]*HD + 2*t);
    float w = aw[e][h];
    a0 = fmaf(w, bf2f((ushort_t)(u & 0xffffu)), a0);
    a1 = fmaf(w, bf2f((ushort_t)(u >> 16)), a1);
  }
  uint32_t pk = (uint32_t)f2bf(a0) | ((uint32_t)f2bf(a1)<<16);
  reinterpret_cast<uint32_t*>(agg_b + ((size_t)i*N1 + d)*HD)[t] = pk;
}

// ---- MFMA GEMM: 128x128 tile, DMA-staged, 2-term (A*Whi + A*Wlo) ----
// BIASMODE: + bias[col], no alpha.  else: fused leaky'd alpha epilogue.
template<bool BIASMODE>
__global__ __launch_bounds__(256) void gemm2(
    const ushort_t* __restrict__ A_b, size_t a_stride,
    const ushort_t* __restrict__ Whi_b, const ushort_t* __restrict__ Wlo_b,
    ushort_t* __restrict__ C_b, size_t c_stride,
    const float* __restrict__ att_b, float* __restrict__ alpha_b, size_t al_stride,
    const float* __restrict__ bias_b)
{
  int i = blockIdx.z;
  int bn0 = blockIdx.x * 128;
  int brow = blockIdx.y * 128;
  const ushort_t* A = A_b + (size_t)i*a_stride;
  const ushort_t* Whi = Whi_b + (size_t)i*HD*HD;
  const ushort_t* Wlo = Wlo_b + (size_t)i*HD*HD;
  ushort_t* C = C_b + (size_t)i*c_stride;

  __shared__ __align__(16) ushort_t smem[2][24*512];
  int t = threadIdx.x, wave = t>>6, lane = t&63;
  int l15 = lane&15, kq = lane>>4;

  int row0 = brow + wave*16 + l15;
  int row1 = brow + (wave+4)*16 + l15;

  const ushort_t* gsrc[6];
  gsrc[0] = A + (size_t)row0*HD + kq*8;
  gsrc[1] = A + (size_t)row1*HD + kq*8;
#pragma unroll
  for (int j=2;j<6;j++){
    int idx = wave + 4*(j-2);
    int ct = idx>>1, h = idx&1;
    const ushort_t* W = h ? Wlo : Whi;
    gsrc[j] = W + (size_t)(bn0 + ct*16 + l15)*HD + kq*8;
  }

  floatx4 acc[4][4];
#pragma unroll
  for (int r=0;r<4;r++)
#pragma unroll
    for (int c=0;c<4;c++) acc[r][c] = (floatx4){0.f,0.f,0.f,0.f};

  int wm = wave>>1, wn = wave&1;

#pragma unroll
  for (int j=0;j<6;j++)
    gload_lds16(gsrc[j], &smem[0][(wave + 4*j)*512] + lane*8);
  __syncthreads();

  for (int cc=0; cc<8; cc++){
    int buf = cc & 1;
    if (cc < 7){
      int k0 = (cc+1)*32;
#pragma unroll
      for (int j=0;j<6;j++)
        gload_lds16(gsrc[j] + k0, &smem[buf^1][(wave + 4*j)*512] + lane*8);
    }
    short8v a[4];
#pragma unroll
    for (int r=0;r<4;r++)
      a[r] = *reinterpret_cast<const short8v*>(&smem[buf][(wm*4+r)*512 + lane*8]);
#pragma unroll
    for (int c=0;c<4;c++){
      int ct = wn*4+c;
      short8v bh = *reinterpret_cast<const short8v*>(&smem[buf][(8+ct*2)*512 + lane*8]);
      short8v bl = *reinterpret_cast<const short8v*>(&smem[buf][(9+ct*2)*512 + lane*8]);
#pragma unroll
      for (int r=0;r<4;r++){
        acc[r][c] = __builtin_amdgcn_mfma_f32_16x16x32_bf16(a[r], bh, acc[r][c], 0,0,0);
        acc[r][c] = __builtin_amdgcn_mfma_f32_16x16x32_bf16(a[r], bl, acc[r][c], 0,0,0);
      }
    }
    __syncthreads();
  }

  float attv[4];
#pragma unroll
  for (int c=0;c<4;c++){
    int col = bn0 + (wn*4+c)*16 + l15;
    if constexpr (BIASMODE) attv[c] = bias_b[i*HD + col];
    else                    attv[c] = att_b[(size_t)i*HD + col];
  }
  int head = (bn0>>6) + wn;
#pragma unroll
  for (int r=0;r<4;r++){
    int rowb = brow + wm*64 + r*16 + kq*4;
#pragma unroll
    for (int j=0;j<4;j++){
      size_t rw = (size_t)(rowb + j)*HD;
#pragma unroll
      for (int c=0;c<4;c++){
        float v = acc[r][c][j];
        if constexpr (BIASMODE) v += attv[c];
        C[rw + bn0 + (wn*4+c)*16 + l15] = f2bf(v);
      }
    }
    if constexpr (!BIASMODE){
#pragma unroll
      for (int j=0;j<4;j++){
        float p = acc[r][0][j]*attv[0] + acc[r][1][j]*attv[1]
                + acc[r][2][j]*attv[2] + acc[r][3][j]*attv[3];
        p += __shfl_xor(p, 1, 64);
        p += __shfl_xor(p, 2, 64);
        p += __shfl_xor(p, 4, 64);
        p += __shfl_xor(p, 8, 64);
        if (l15 == 0){
          float lg = p > 0.f ? p : 0.2f*p;
          alpha_b[(size_t)i*al_stride + (size_t)(rowb + j)*4 + head] = lg;
        }
      }
    }
  }
}

// ---- layer-1 GAT message: fused gate + accumulate over modalities -> xmod fp32 ----
__global__ __launch_bounds__(128) void gat_msg1(
    const ushort_t* __restrict__ xl1hi, const float* __restrict__ alpha1,
    const int* __restrict__ e1src, const float* __restrict__ gat_b,
    const uint32_t* __restrict__ g0_u, const float* __restrict__ coef,
    float* __restrict__ xmod)
{
  int d = blockIdx.x, t = threadIdx.x;
  __shared__ int src[16];
  __shared__ float aw[16][4];
  float o0 = 0.f, o1 = 0.f;
  for (int i=0;i<NM;i++){
    if (t < 16) src[t] = e1src[(size_t)i*E1 + d*16 + t];
    __syncthreads();
    if (t < 64){
      int e = t&15, h = t>>4;
      float l = alpha1[((size_t)i*N1 + src[e])*4 + h];
      float m = l;
#pragma unroll
      for (int off=1; off<16; off<<=1) m = fmaxf(m, __shfl_xor(m, off, 64));
      float ex = expf(l - m);
      float s = ex;
#pragma unroll
      for (int off=1; off<16; off<<=1) s += __shfl_xor(s, off, 64);
      aw[e][h] = ex / (s + 1e-16f);
    }
    __syncthreads();
    const ushort_t* xl = xl1hi + (size_t)i*N1*HD;
    int h = t >> 5;
    float a0=0.f, a1=0.f;
#pragma unroll
    for (int e=0;e<16;e++){
      uint32_t u = *reinterpret_cast<const uint32_t*>(xl + (size_t)src[e]*HD + 2*t);
      float w = aw[e][h];
      a0 = fmaf(w, bf2f((ushort_t)(u & 0xffffu)), a0);
      a1 = fmaf(w, bf2f((ushort_t)(u >> 16)), a1);
    }
    uint32_t gh = g0_u[((size_t)i*N1 + d)*128 + t];
    float g00 = bf2f((ushort_t)(gh & 0xffffu));
    float g01 = bf2f((ushort_t)(gh >> 16));
    const float* bias = gat_b + i*HD;
    float cv = coef[d*3 + i];
    o0 += cv*(2.f*g00 + 2.f*(a0 + bias[2*t]));
    o1 += cv*(2.f*g01 + 2.f*(a1 + bias[2*t+1]));
    __syncthreads();
  }
  *reinterpret_cast<float2*>(&xmod[(size_t)d*HD + 2*t]) = make_float2(o0, o1);
}

// ---- emb = xmod @ embW^T + b; writes fp32 + hi/lo bf16 ----
__global__ __launch_bounds__(256) void emb_gemm(
  const float* __restrict__ xmod, const float* __restrict__ wT,
  const float* __restrict__ eb, float* __restrict__ emb,
  ushort_t* __restrict__ ehi, ushort_t* __restrict__ elo)
{
  __shared__ float xs[32][260];
  int t = threadIdx.x;
  int brow = blockIdx.x * 32;
#pragma unroll
  for (int j=0;j<8;j++){
    int linear = j*256+t;
    int row = linear >> 6;
    int kq = linear & 63;
    float4 f = *reinterpret_cast<const float4*>(&xmod[(size_t)(brow+row)*256 + kq*4]);
    xs[row][kq*4+0]=f.x; xs[row][kq*4+1]=f.y; xs[row][kq*4+2]=f.z; xs[row][kq*4+3]=f.w;
  }
  __syncthreads();
  int tj = t & 127, th = t >> 7;
  float acc[16];
#pragma unroll
  for(int r=0;r<16;r++) acc[r]=0.f;
  for (int k=0;k<256;k++){
    float w = wT[k*128 + tj];
#pragma unroll
    for (int r=0;r<16;r++) acc[r] = fmaf(xs[th*16+r][k], w, acc[r]);
  }
  float bias = eb[tj];
#pragma unroll
  for (int r=0;r<16;r++){
    size_t idx = (size_t)(brow+th*16+r)*128 + tj;
    float v = acc[r] + bias;
    emb[idx] = v;
    ushort_t hb = f2bf(v);
    ehi[idx] = hb;
    elo[idx] = f2bf(v - bf2f(hb));
  }
}

// ---- dot = emb @ emb^T via MFMA, 3-term split ----
__global__ __launch_bounds__(256) void dot_mfma(
    const ushort_t* __restrict__ Ehi, const ushort_t* __restrict__ Elo,
    float* __restrict__ dot)
{
  __shared__ __align__(16) ushort_t lb[2][16384];
  int t = threadIdx.x, wave = t>>6, lane = t&63;
  int arow0 = blockIdx.y*128, brow0 = blockIdx.x*128;
  {
    const ushort_t* srcp = (t<128) ? Ehi : Elo;
    ushort_t* dstb = lb[(t<128)?0:1];
    int o = t & 127;
    const ushort_t* rp = srcp + (size_t)(brow0+o)*128;
#pragma unroll
    for (int g=0; g<16; g++){
      short8v v = *reinterpret_cast<const short8v*>(rp + g*8);
      int c = g>>2, grp = g&3;
      int lidx = c*4096 + (o>>4)*512 + ((grp<<4)|(o&15))*8;
      *reinterpret_cast<short8v*>(&dstb[lidx]) = v;
    }
  }
  __syncthreads();

  floatx4 acc[2][8];
#pragma unroll
  for (int rt=0;rt<2;rt++)
#pragma unroll
    for (int ot=0;ot<8;ot++) acc[rt][ot] = (floatx4){0.f,0.f,0.f,0.f};

  int ar0 = arow0 + wave*32 + (lane&15);
  int ar1 = ar0 + 16;
  int koff = (lane>>4)*8;
#pragma unroll
  for (int c=0;c<4;c++){
    short8v ah0 = *reinterpret_cast<const short8v*>(Ehi + (size_t)ar0*128 + c*32 + koff);
    short8v ah1 = *reinterpret_cast<const short8v*>(Ehi + (size_t)ar1*128 + c*32 + koff);
    short8v al0 = *reinterpret_cast<const short8v*>(Elo + (size_t)ar0*128 + c*32 + koff);
    short8v al1 = *reinterpret_cast<const short8v*>(Elo + (size_t)ar1*128 + c*32 + koff);
#pragma unroll
    for (int ot=0;ot<8;ot++){
      short8v bh = *reinterpret_cast<const short8v*>(&lb[0][c*4096 + ot*512 + lane*8]);
      short8v bl = *reinterpret_cast<const short8v*>(&lb[1][c*4096 + ot*512 + lane*8]);
      acc[0][ot] = __builtin_amdgcn_mfma_f32_16x16x32_bf16(ah0, bh, acc[0][ot], 0,0,0);
      acc[0][ot] = __builtin_amdgcn_mfma_f32_16x16x32_bf16(ah0, bl, acc[0][ot], 0,0,0);
      acc[0][ot] = __builtin_amdgcn_mfma_f32_16x16x32_bf16(al0, bh, acc[0][ot], 0,0,0);
      acc[1][ot] = __builtin_amdgcn_mfma_f32_16x16x32_bf16(ah1, bh, acc[1][ot], 0,0,0);
      acc[1][ot] = __builtin_amdgcn_mfma_f32_16x16x32_bf16(ah1, bl, acc[1][ot], 0,0,0);
      acc[1][ot] = __builtin_amdgcn_mfma_f32_16x16x32_bf16(al1, bh, acc[1][ot], 0,0,0);
    }
  }
#pragma unroll
  for (int rt=0;rt<2;rt++){
    int rb = arow0 + wave*32 + rt*16 + (lane>>4)*4;
#pragma unroll
    for (int r=0;r<4;r++)
#pragma unroll
      for (int ot=0;ot<8;ot++)
        dot[(size_t)(rb+r)*4096 + brow0 + ot*16 + (lane&15)] = acc[rt][ot][r];
  }
}

extern "C" void kernel_launch(void* const* d_in, const int* in_sizes, int n_in,
                              void* d_out, int out_size, void* d_ws, size_t ws_size,
                              hipStream_t stream) {
  (void)in_sizes; (void)n_in; (void)out_size; (void)ws_size;
  const float* masks   = (const float*)d_in[0];
  const int*   n_ids   = (const int*)d_in[1];
  const int*   e0_src  = (const int*)d_in[2];
  const int*   e1_src  = (const int*)d_in[4];
  const float* pre_W   = (const float*)d_in[6];
  const float* pre_b   = (const float*)d_in[7];
  const float* gat_W   = (const float*)d_in[8];
  const float* gat_att = (const float*)d_in[9];
  const float* gat_b   = (const float*)d_in[10];
  const float* sp      = (const float*)d_in[11];
  const float* emb_W   = (const float*)d_in[12];
  const float* emb_b   = (const float*)d_in[13];

  float* out = (float*)d_out;
  float* dot = out;                         // [4096*4096]
  float* emb = out + (size_t)NB*NB;         // [4096*128]
  float* scales_out = emb + (size_t)NB*128; // [3]

  char* p = (char*)d_ws;
  auto alloc = [&](size_t bytes)->char*{ char* r = p; p += (bytes + 255) & ~(size_t)255; return r; };
  ushort_t* WT    = (ushort_t*)alloc((size_t)NM*PADC*HD*2);
  float*    alphG4= (float*)alloc((size_t)NM*4*PADC*4*4);
  ushort_t* agg   = (ushort_t*)alloc((size_t)NM*N1*HD*2);
  uint32_t* g0u   = (uint32_t*)alloc((size_t)NM*N1*HD*2);
  ushort_t* xl1hi = (ushort_t*)alloc((size_t)NM*N1*HD*2);
  float*    alph1 = (float*)alloc((size_t)NM*N1*4*4);
  float*    xmod  = (float*)alloc((size_t)NB*HD*4);
  float*    coef  = (float*)alloc((size_t)NB*3*4);
  float*    wT    = (float*)alloc((size_t)HD*128*4);
  ushort_t* gWhi  = (ushort_t*)alloc((size_t)NM*HD*HD*2);
  ushort_t* gWlo  = (ushort_t*)alloc((size_t)NM*HD*HD*2);
  float*    bsum  = (float*)alloc((size_t)NM*HD*4);
  float*    batt  = (float*)alloc((size_t)NM*4*4);
  float*    watt  = (float*)alloc((size_t)NM*1024*4);
  ushort_t* ehi   = (ushort_t*)alloc((size_t)NB*128*2);
  ushort_t* elo   = (ushort_t*)alloc((size_t)NB*128*2);

  prep_k<<<927, 256, 0, stream>>>(masks, sp, coef, scales_out, emb_W, wT,
                                  gat_W, gWhi, gWlo, pre_b, gat_att, gat_b,
                                  bsum, batt, watt);
  transpB_k<<<dim3((PADC+255)/256, 4, NM), 256, 0, stream>>>(pre_W, watt, WT, alphG4);
  gat_msg0w<<<dim3(N1, NM), 128, 0, stream>>>(WT, alphG4, batt, n_ids, e0_src, agg);
  gemm2<true><<<dim3(2, N1/128, NM), 256, 0, stream>>>(
      agg, (size_t)N1*HD, gWhi, gWlo,
      (ushort_t*)g0u, (size_t)N1*HD, nullptr, nullptr, 0, bsum);
  gemm2<false><<<dim3(2, N1/128, NM), 256, 0, stream>>>(
      (const ushort_t*)g0u, (size_t)N1*HD, gWhi, gWlo,
      xl1hi, (size_t)N1*HD, gat_att, alph1, (size_t)N1*4, nullptr);
  gat_msg1<<<NB, 128, 0, stream>>>(xl1hi, alph1, e1_src, gat_b, g0u, coef, xmod);
  emb_gemm<<<NB/32, 256, 0, stream>>>(xmod, wT, emb_b, emb, ehi, elo);
  dot_mfma<<<dim3(32,32), 256, 0, stream>>>(ehi, elo, dot);
}

// Round 21
// 238.326 us; speedup vs baseline: 1.1276x; 1.1276x over previous
//
#include <hip/hip_runtime.h>
#include <hip/hip_bf16.h>
#include <cstdint>

#define IN_SZ 50000
#define PADC  50048
#define NM 3
#define N0 40960
#define N1 16384
#define NB 4096
#define HD 256
#define DEG 16
#define E0 (N1*DEG)
#define E1 (NB*DEG)

using short8v = __attribute__((ext_vector_type(8))) short;
using floatx4 = __attribute__((ext_vector_type(4))) float;
typedef unsigned short ushort_t;

__device__ __forceinline__ ushort_t f2bf(float f){
  uint32_t u = __float_as_uint(f);
  uint32_t r = u + 0x7FFFu + ((u>>16)&1u);
  return (ushort_t)(r>>16);
}
__device__ __forceinline__ float bf2f(ushort_t h){
  return __uint_as_float(((uint32_t)h)<<16);
}
__device__ __forceinline__ void gload_lds16(const void* g, void* l){
  __builtin_amdgcn_global_load_lds(
      (const __attribute__((address_space(1))) void*)g,
      (__attribute__((address_space(3))) void*)l, 16, 0, 0);
}

// ---------------- threefry2x32 (JAX-exact) ----------------
__device__ __forceinline__ uint32_t rotl32(uint32_t x, uint32_t d){ return (x<<d)|(x>>(32u-d)); }

__device__ void tf2x32(uint32_t k0, uint32_t k1, uint32_t c0, uint32_t c1,
                       uint32_t& y0, uint32_t& y1)
{
  uint32_t ks2 = k0 ^ k1 ^ 0x1BD11BDAu;
  uint32_t x0 = c0 + k0, x1 = c1 + k1;
#define R4(a,b,c,d) \
  x0+=x1; x1=rotl32(x1,a); x1^=x0; \
  x0+=x1; x1=rotl32(x1,b); x1^=x0; \
  x0+=x1; x1=rotl32(x1,c); x1^=x0; \
  x0+=x1; x1=rotl32(x1,d); x1^=x0;
  R4(13,15,26,6)  x0+=k1;  x1+=ks2+1u;
  R4(17,29,16,24) x0+=ks2; x1+=k0+2u;
  R4(13,15,26,6)  x0+=k0;  x1+=k1+3u;
  R4(17,29,16,24) x0+=k1;  x1+=ks2+4u;
  R4(13,15,26,6)  x0+=ks2; x1+=k0+5u;
#undef R4
  y0=x0; y1=x1;
}

// ---- merged prep: [0,16) interp | [16,144) embW transpose | [144,912) split | [912,915) bias ----
__global__ __launch_bounds__(256) void prep_k(
    const float* __restrict__ masks, const float* __restrict__ sp,
    float* __restrict__ coef, float* __restrict__ scales_out,
    const float* __restrict__ emb_W, float* __restrict__ wT,
    const float* __restrict__ gat_W, ushort_t* __restrict__ gWhi, ushort_t* __restrict__ gWlo,
    const float* __restrict__ pre_b, const float* __restrict__ gat_att,
    const float* __restrict__ gat_b, float* __restrict__ bsum, float* __restrict__ batt)
{
  int blk = blockIdx.x;
  int t = threadIdx.x;
  if (blk < 16){
    int b = blk*256 + t;
    float s0=sp[0], s1=sp[1], s2=sp[2];
    float mx = fmaxf(s0,fmaxf(s1,s2));
    float e0=expf(s0-mx), e1=expf(s1-mx), e2=expf(s2-mx);
    float inv = 1.f/(e0+e1+e2);
    float sc[3] = {e0*inv, e1*inv, e2*inv};
    if (b == 0){ scales_out[0]=sc[0]; scales_out[1]=sc[1]; scales_out[2]=sc[2]; }
    uint32_t bits[3];
    uint32_t K0,K1, t0,t1;
    tf2x32(0u,42u,0u,1u,K0,K1);
    for (int i=0;i<3;i++){
      uint32_t idx = (uint32_t)(b*3+i);
      tf2x32(K0,K1,0u,idx,t0,t1);
      bits[i] = (t0 ^ t1) & 1u;
    }
    float mk[3] = {masks[b*3+0], masks[b*3+1], masks[b*3+2]};
    float msum = mk[0]+mk[1]+mk[2];
    float rs = (float)(bits[0]+bits[1]+bits[2]);
    float add = powf(1.f/(1.f+rs), 20.f) + powf(1.f/msum, 20.f);
    float lg[3]; float lmax = -1e30f;
    for (int i=0;i<3;i++){
      float rm = floorf((float)bits[i] + add);
      rm = rm/(rm+1e-10f);
      float mm = mk[i]*rm;
      lg[i] = mm + (1.f-mm)*(-1e10f);
      lmax = fmaxf(lmax, lg[i]);
    }
    float es[3], ssum=0.f;
    for (int i=0;i<3;i++){ es[i]=expf(lg[i]-lmax); ssum+=es[i]; }
    for (int i=0;i<3;i++) coef[b*3+i] = sc[i]*es[i]/ssum;
  } else if (blk < 144){
    int g = (blk-16)*256 + t;
    int j = g >> 8, k = g & 255;
    wT[k*128 + j] = emb_W[g];
  } else if (blk < 912){
    int g = (blk-144)*256 + t;
    float v = gat_W[g];
    ushort_t h = f2bf(v);
    gWhi[g] = h;
    gWlo[g] = f2bf(v - bf2f(h));
  } else {
    int i = blk - 912, o = t;
    const float* W = gat_W + (size_t)i*HD*HD + (size_t)o*HD;
    const float* b = pre_b + i*HD;
    float s = 0.f;
    for (int k=0;k<HD;k++) s = fmaf(b[k], W[k], s);
    bsum[i*HD + o] = s + gat_b[i*HD + o];
    __shared__ float red[256];
    red[o] = s * gat_att[i*HD + o];
    __syncthreads();
    if (o < 4){
      float p = 0.f;
      for (int j=0;j<64;j++) p += red[o*64 + j];
      batt[i*4 + o] = p;
    }
  }
}

// ---- fused transpose + GT GEMM v3: 128-col blocks + counted-vmcnt pipeline ----
// GT[c,o] = sum_k preW[k,c]*gatW_hi[o,k]. A: fp32 [32k x 128c] chunks DMA'd with
// source-quad swizzle; transposed at ds_read time. Per chunk: issue next (8 DMA),
// s_waitcnt vmcnt(8) (next chunk stays in flight across barrier), raw s_barrier,
// compute, end s_barrier. cvt via v_cvt_pk_bf16_f32.
__global__ __launch_bounds__(256) void gt_fused(
    const float* __restrict__ preW_b,
    const ushort_t* __restrict__ Whi_b,
    const float* __restrict__ att_b, const float* __restrict__ batt,
    ushort_t* __restrict__ GT_b, float* __restrict__ alphaG_b)
{
  int i = blockIdx.z;
  int brow = blockIdx.x * 128;
  const float* pw = preW_b + (size_t)i*HD*IN_SZ;
  const ushort_t* Whi = Whi_b + (size_t)i*HD*HD;
  const float* att = att_b + (size_t)i*HD;
  ushort_t* GT = GT_b + (size_t)i*(size_t)PADC*HD;
  float* alphaG = alphaG_b + (size_t)i*IN_SZ*4;

  __shared__ __align__(16) float    As[2][32*128];   // 16 KB x2
  __shared__ __align__(16) ushort_t Bs[2][16*512];   // 16 KB x2  (64 KB -> 2 blk/CU)
  int t = threadIdx.x, wave = t>>6, lane = t&63;
  int l15 = lane&15, kq = lane>>4;

  int aRow[4]; int aCol[4];
#pragma unroll
  for (int r=0;r<4;r++){
    int lin = r*256 + t;
    aRow[r] = lin >> 5;
    int colq = lin & 31;
    int srcc = brow + ((colq ^ (((aRow[r]>>3)&3)<<2)) << 2);
    if (srcc > IN_SZ-4) srcc = IN_SZ-4;
    aCol[r] = srcc;
  }
  const ushort_t* bSrc[4];
#pragma unroll
  for (int r=0;r<4;r++){
    int f = wave + r*4;
    bSrc[r] = Whi + (size_t)(f*16 + l15)*HD + kq*8;
  }

  floatx4 acc[2][16];
#pragma unroll
  for (int r=0;r<2;r++)
#pragma unroll
    for (int ot=0;ot<16;ot++) acc[r][ot] = (floatx4){0.f,0.f,0.f,0.f};

  int clds[2];
#pragma unroll
  for (int r=0;r<2;r++){
    int rt = wave*2 + r;
    clds[r] = (((rt*4 + (l15>>2)) ^ (kq<<2)) << 2) + (l15 & 3);
  }

  // 8 DMA instructions per thread per chunk, program-ordered
  auto issue = [&](int cc, int bufi){
    int k0 = cc*32;
#pragma unroll
    for (int r=0;r<4;r++)
      gload_lds16(pw + (size_t)(k0 + aRow[r])*IN_SZ + aCol[r],
                  &As[bufi][(r*256 + wave*64)*4] + lane*4);
#pragma unroll
    for (int r=0;r<4;r++)
      gload_lds16(bSrc[r] + k0, &Bs[bufi][(wave + r*4)*512] + lane*8);
  };

  issue(0, 0);   // prologue

  for (int cc=0; cc<8; cc++){
    int buf = cc & 1;
    if (cc < 7) issue(cc + 1, buf ^ 1);   // prefetch; stays in flight across barrier
    if (cc < 7) asm volatile("s_waitcnt vmcnt(8)" ::: "memory");
    else        asm volatile("s_waitcnt vmcnt(0)" ::: "memory");
    __builtin_amdgcn_sched_barrier(0);
    __builtin_amdgcn_s_barrier();          // all waves' chunk-cc data in LDS
    __builtin_amdgcn_sched_barrier(0);

    short8v a[2];
#pragma unroll
    for (int r=0;r<2;r++){
      float af[8];
#pragma unroll
      for (int j=0;j<8;j++) af[j] = As[buf][(kq*8+j)*128 + clds[r]];
      union { uint32_t u[4]; short8v v; } cv;
#pragma unroll
      for (int j=0;j<4;j++)
        asm("v_cvt_pk_bf16_f32 %0, %1, %2" : "=v"(cv.u[j]) : "v"(af[2*j]), "v"(af[2*j+1]));
      a[r] = cv.v;
    }
#pragma unroll
    for (int ot=0;ot<16;ot++){
      short8v bh = *reinterpret_cast<const short8v*>(&Bs[buf][ot*512 + lane*8]);
      acc[0][ot] = __builtin_amdgcn_mfma_f32_16x16x32_bf16(a[0], bh, acc[0][ot], 0,0,0);
      acc[1][ot] = __builtin_amdgcn_mfma_f32_16x16x32_bf16(a[1], bh, acc[1][ot], 0,0,0);
    }
    __builtin_amdgcn_sched_barrier(0);
    __builtin_amdgcn_s_barrier();          // reads of buf done -> next issue may overwrite
  }

  // epilogue
  float attv[16];
#pragma unroll
  for (int ot=0;ot<16;ot++) attv[ot] = att[ot*16 + l15];
#pragma unroll
  for (int r=0;r<2;r++){
    int rbase = brow + (wave*2+r)*16 + kq*4;
#pragma unroll
    for (int jj=0;jj<4;jj++){
      int c = rbase + jj;
      bool ok = c < IN_SZ;
      size_t rw = (size_t)c*HD;
      if (ok){
#pragma unroll
        for (int ot=0;ot<16;ot++) GT[rw + ot*16 + l15] = f2bf(acc[r][ot][jj]);
      }
#pragma unroll
      for (int h=0;h<4;h++){
        float p = acc[r][4*h+0][jj]*attv[4*h+0] + acc[r][4*h+1][jj]*attv[4*h+1]
                + acc[r][4*h+2][jj]*attv[4*h+2] + acc[r][4*h+3][jj]*attv[4*h+3];
        p += __shfl_xor(p, 1, 64);
        p += __shfl_xor(p, 2, 64);
        p += __shfl_xor(p, 4, 64);
        p += __shfl_xor(p, 8, 64);
        if (l15 == 0 && ok){
          p += batt[i*4 + h];
          alphaG[(size_t)c*4 + h] = p > 0.f ? p : 0.2f*p;
        }
      }
    }
  }
}

// ---- MFMA GEMM (layer 1): 128x128 tile, DMA-staged, 2-term ----
__global__ __launch_bounds__(256) void gemm2(
    const ushort_t* __restrict__ A_b, size_t a_stride,
    const ushort_t* __restrict__ Whi_b, const ushort_t* __restrict__ Wlo_b,
    ushort_t* __restrict__ C_b, size_t c_stride,
    const float* __restrict__ att_b, float* __restrict__ alpha_b, size_t al_stride)
{
  int i = blockIdx.z;
  int bn0 = blockIdx.x * 128;
  int brow = blockIdx.y * 128;
  const ushort_t* A = A_b + (size_t)i*a_stride;
  const ushort_t* Whi = Whi_b + (size_t)i*HD*HD;
  const ushort_t* Wlo = Wlo_b + (size_t)i*HD*HD;
  ushort_t* C = C_b + (size_t)i*c_stride;
  const float* att = att_b + (size_t)i*HD;
  float* alpha = alpha_b + (size_t)i*al_stride;

  __shared__ __align__(16) ushort_t smem[2][24*512];
  int t = threadIdx.x, wave = t>>6, lane = t&63;
  int l15 = lane&15, kq = lane>>4;

  int row0 = brow + wave*16 + l15;
  int row1 = brow + (wave+4)*16 + l15;

  const ushort_t* gsrc[6];
  gsrc[0] = A + (size_t)row0*HD + kq*8;
  gsrc[1] = A + (size_t)row1*HD + kq*8;
#pragma unroll
  for (int j=2;j<6;j++){
    int idx = wave + 4*(j-2);
    int ct = idx>>1, h = idx&1;
    const ushort_t* W = h ? Wlo : Whi;
    gsrc[j] = W + (size_t)(bn0 + ct*16 + l15)*HD + kq*8;
  }

  floatx4 acc[4][4];
#pragma unroll
  for (int r=0;r<4;r++)
#pragma unroll
    for (int c=0;c<4;c++) acc[r][c] = (floatx4){0.f,0.f,0.f,0.f};

  int wm = wave>>1, wn = wave&1;

#pragma unroll
  for (int j=0;j<6;j++)
    gload_lds16(gsrc[j], &smem[0][(wave + 4*j)*512] + lane*8);
  __syncthreads();

  for (int cc=0; cc<8; cc++){
    int buf = cc & 1;
    if (cc < 7){
      int k0 = (cc+1)*32;
#pragma unroll
      for (int j=0;j<6;j++)
        gload_lds16(gsrc[j] + k0, &smem[buf^1][(wave + 4*j)*512] + lane*8);
    }
    short8v a[4];
#pragma unroll
    for (int r=0;r<4;r++)
      a[r] = *reinterpret_cast<const short8v*>(&smem[buf][(wm*4+r)*512 + lane*8]);
#pragma unroll
    for (int c=0;c<4;c++){
      int ct = wn*4+c;
      short8v bh = *reinterpret_cast<const short8v*>(&smem[buf][(8+ct*2)*512 + lane*8]);
      short8v bl = *reinterpret_cast<const short8v*>(&smem[buf][(9+ct*2)*512 + lane*8]);
#pragma unroll
      for (int r=0;r<4;r++){
        acc[r][c] = __builtin_amdgcn_mfma_f32_16x16x32_bf16(a[r], bh, acc[r][c], 0,0,0);
        acc[r][c] = __builtin_amdgcn_mfma_f32_16x16x32_bf16(a[r], bl, acc[r][c], 0,0,0);
      }
    }
    __syncthreads();
  }

  float attv[4];
#pragma unroll
  for (int c=0;c<4;c++) attv[c] = att[bn0 + (wn*4+c)*16 + l15];
  int head = (bn0>>6) + wn;
#pragma unroll
  for (int r=0;r<4;r++){
    int rowb = brow + wm*64 + r*16 + kq*4;
#pragma unroll
    for (int j=0;j<4;j++){
      size_t rw = (size_t)(rowb + j)*HD;
#pragma unroll
      for (int c=0;c<4;c++)
        C[rw + bn0 + (wn*4+c)*16 + l15] = f2bf(acc[r][c][j]);
    }
#pragma unroll
    for (int j=0;j<4;j++){
      float p = acc[r][0][j]*attv[0] + acc[r][1][j]*attv[1]
              + acc[r][2][j]*attv[2] + acc[r][3][j]*attv[3];
      p += __shfl_xor(p, 1, 64);
      p += __shfl_xor(p, 2, 64);
      p += __shfl_xor(p, 4, 64);
      p += __shfl_xor(p, 8, 64);
      if (l15 == 0){
        float lg = p > 0.f ? p : 0.2f*p;
        alpha[(size_t)(rowb + j)*4 + head] = lg;
      }
    }
  }
}

// ---- layer-0 GAT message: gathers GT rows via n_ids-remapped sources ----
__global__ __launch_bounds__(128) void gat_msg0(
    const ushort_t* __restrict__ GT_b, const float* __restrict__ alphaG_b,
    const int* __restrict__ n_ids, const int* __restrict__ esrc_b,
    const float* __restrict__ bsum_b, uint32_t* __restrict__ g0_u)
{
  int i = blockIdx.y, d = blockIdx.x, t = threadIdx.x;
  const ushort_t* GT = GT_b + (size_t)i*(size_t)PADC*HD;
  const float* alphaG = alphaG_b + (size_t)i*IN_SZ*4;
  const float* bsum = bsum_b + i*HD;
  __shared__ int src[16];
  __shared__ float aw[16][4];
  if (t < 16) src[t] = n_ids[(size_t)i*N0 + esrc_b[(size_t)i*E0 + d*16 + t]];
  __syncthreads();
  if (t < 64){
    int e = t&15, h = t>>4;
    float l = alphaG[(size_t)src[e]*4 + h];
    float m = l;
#pragma unroll
    for (int off=1; off<16; off<<=1) m = fmaxf(m, __shfl_xor(m, off, 64));
    float ex = expf(l - m);
    float s = ex;
#pragma unroll
    for (int off=1; off<16; off<<=1) s += __shfl_xor(s, off, 64);
    aw[e][h] = ex / (s + 1e-16f);
  }
  __syncthreads();
  int h = t >> 5;
  float a0=0.f, a1=0.f;
#pragma unroll
  for (int e=0;e<16;e++){
    uint32_t u = *reinterpret_cast<const uint32_t*>(GT + (size_t)src[e]*HD + 2*t);
    float w = aw[e][h];
    a0 = fmaf(w, bf2f((ushort_t)(u & 0xffffu)), a0);
    a1 = fmaf(w, bf2f((ushort_t)(u >> 16)), a1);
  }
  float v0 = a0 + bsum[2*t], v1 = a1 + bsum[2*t+1];
  g0_u[((size_t)i*N1 + d)*128 + t] = (uint32_t)f2bf(v0) | ((uint32_t)f2bf(v1)<<16);
}

// ---- layer-1 GAT message: fused gate + accumulate over modalities -> xmod fp32 ----
__global__ __launch_bounds__(128) void gat_msg1(
    const ushort_t* __restrict__ xl1hi, const float* __restrict__ alpha1,
    const int* __restrict__ e1src, const float* __restrict__ gat_b,
    const uint32_t* __restrict__ g0_u, const float* __restrict__ coef,
    float* __restrict__ xmod)
{
  int d = blockIdx.x, t = threadIdx.x;
  __shared__ int src[16];
  __shared__ float aw[16][4];
  float o0 = 0.f, o1 = 0.f;
  for (int i=0;i<NM;i++){
    if (t < 16) src[t] = e1src[(size_t)i*E1 + d*16 + t];
    __syncthreads();
    if (t < 64){
      int e = t&15, h = t>>4;
      float l = alpha1[((size_t)i*N1 + src[e])*4 + h];
      float m = l;
#pragma unroll
      for (int off=1; off<16; off<<=1) m = fmaxf(m, __shfl_xor(m, off, 64));
      float ex = expf(l - m);
      float s = ex;
#pragma unroll
      for (int off=1; off<16; off<<=1) s += __shfl_xor(s, off, 64);
      aw[e][h] = ex / (s + 1e-16f);
    }
    __syncthreads();
    const ushort_t* xl = xl1hi + (size_t)i*N1*HD;
    int h = t >> 5;
    float a0=0.f, a1=0.f;
#pragma unroll
    for (int e=0;e<16;e++){
      uint32_t u = *reinterpret_cast<const uint32_t*>(xl + (size_t)src[e]*HD + 2*t);
      float w = aw[e][h];
      a0 = fmaf(w, bf2f((ushort_t)(u & 0xffffu)), a0);
      a1 = fmaf(w, bf2f((ushort_t)(u >> 16)), a1);
    }
    uint32_t gh = g0_u[((size_t)i*N1 + d)*128 + t];
    float g00 = bf2f((ushort_t)(gh & 0xffffu));
    float g01 = bf2f((ushort_t)(gh >> 16));
    const float* bias = gat_b + i*HD;
    float cv = coef[d*3 + i];
    o0 += cv*(2.f*g00 + 2.f*(a0 + bias[2*t]));
    o1 += cv*(2.f*g01 + 2.f*(a1 + bias[2*t+1]));
    __syncthreads();
  }
  *reinterpret_cast<float2*>(&xmod[(size_t)d*HD + 2*t]) = make_float2(o0, o1);
}

// ---- emb = xmod @ embW^T + b; writes fp32 + hi/lo bf16 ----
__global__ __launch_bounds__(256) void emb_gemm(
  const float* __restrict__ xmod, const float* __restrict__ wT,
  const float* __restrict__ eb, float* __restrict__ emb,
  ushort_t* __restrict__ ehi, ushort_t* __restrict__ elo)
{
  __shared__ float xs[32][260];
  int t = threadIdx.x;
  int brow = blockIdx.x * 32;
#pragma unroll
  for (int j=0;j<8;j++){
    int linear = j*256+t;
    int row = linear >> 6;
    int kq = linear & 63;
    float4 f = *reinterpret_cast<const float4*>(&xmod[(size_t)(brow+row)*256 + kq*4]);
    xs[row][kq*4+0]=f.x; xs[row][kq*4+1]=f.y; xs[row][kq*4+2]=f.z; xs[row][kq*4+3]=f.w;
  }
  __syncthreads();
  int tj = t & 127, th = t >> 7;
  float acc[16];
#pragma unroll
  for(int r=0;r<16;r++) acc[r]=0.f;
  for (int k=0;k<256;k++){
    float w = wT[k*128 + tj];
#pragma unroll
    for (int r=0;r<16;r++) acc[r] = fmaf(xs[th*16+r][k], w, acc[r]);
  }
  float bias = eb[tj];
#pragma unroll
  for (int r=0;r<16;r++){
    size_t idx = (size_t)(brow+th*16+r)*128 + tj;
    float v = acc[r] + bias;
    emb[idx] = v;
    ushort_t hb = f2bf(v);
    ehi[idx] = hb;
    elo[idx] = f2bf(v - bf2f(hb));
  }
}

// ---- dot = emb @ emb^T via MFMA, 3-term split ----
__global__ __launch_bounds__(256) void dot_mfma(
    const ushort_t* __restrict__ Ehi, const ushort_t* __restrict__ Elo,
    float* __restrict__ dot)
{
  __shared__ __align__(16) ushort_t lb[2][16384];
  int t = threadIdx.x, wave = t>>6, lane = t&63;
  int arow0 = blockIdx.y*128, brow0 = blockIdx.x*128;
  {
    const ushort_t* srcp = (t<128) ? Ehi : Elo;
    ushort_t* dstb = lb[(t<128)?0:1];
    int o = t & 127;
    const ushort_t* rp = srcp + (size_t)(brow0+o)*128;
#pragma unroll
    for (int g=0; g<16; g++){
      short8v v = *reinterpret_cast<const short8v*>(rp + g*8);
      int c = g>>2, grp = g&3;
      int lidx = c*4096 + (o>>4)*512 + ((grp<<4)|(o&15))*8;
      *reinterpret_cast<short8v*>(&dstb[lidx]) = v;
    }
  }
  __syncthreads();

  floatx4 acc[2][8];
#pragma unroll
  for (int rt=0;rt<2;rt++)
#pragma unroll
    for (int ot=0;ot<8;ot++) acc[rt][ot] = (floatx4){0.f,0.f,0.f,0.f};

  int ar0 = arow0 + wave*32 + (lane&15);
  int ar1 = ar0 + 16;
  int koff = (lane>>4)*8;
#pragma unroll
  for (int c=0;c<4;c++){
    short8v ah0 = *reinterpret_cast<const short8v*>(Ehi + (size_t)ar0*128 + c*32 + koff);
    short8v ah1 = *reinterpret_cast<const short8v*>(Ehi + (size_t)ar1*128 + c*32 + koff);
    short8v al0 = *reinterpret_cast<const short8v*>(Elo + (size_t)ar0*128 + c*32 + koff);
    short8v al1 = *reinterpret_cast<const short8v*>(Elo + (size_t)ar1*128 + c*32 + koff);
#pragma unroll
    for (int ot=0;ot<8;ot++){
      short8v bh = *reinterpret_cast<const short8v*>(&lb[0][c*4096 + ot*512 + lane*8]);
      short8v bl = *reinterpret_cast<const short8v*>(&lb[1][c*4096 + ot*512 + lane*8]);
      acc[0][ot] = __builtin_amdgcn_mfma_f32_16x16x32_bf16(ah0, bh, acc[0][ot], 0,0,0);
      acc[0][ot] = __builtin_amdgcn_mfma_f32_16x16x32_bf16(ah0, bl, acc[0][ot], 0,0,0);
      acc[0][ot] = __builtin_amdgcn_mfma_f32_16x16x32_bf16(al0, bh, acc[0][ot], 0,0,0);
      acc[1][ot] = __builtin_amdgcn_mfma_f32_16x16x32_bf16(ah1, bh, acc[1][ot], 0,0,0);
      acc[1][ot] = __builtin_amdgcn_mfma_f32_16x16x32_bf16(ah1, bl, acc[1][ot], 0,0,0);
      acc[1][ot] = __builtin_amdgcn_mfma_f32_16x16x32_bf16(al1, bh, acc[1][ot], 0,0,0);
    }
  }
#pragma unroll
  for (int rt=0;rt<2;rt++){
    int rb = arow0 + wave*32 + rt*16 + (lane>>4)*4;
#pragma unroll
    for (int r=0;r<4;r++)
#pragma unroll
      for (int ot=0;ot<8;ot++)
        dot[(size_t)(rb+r)*4096 + brow0 + ot*16 + (lane&15)] = acc[rt][ot][r];
  }
}

extern "C" void kernel_launch(void* const* d_in, const int* in_sizes, int n_in,
                              void* d_out, int out_size, void* d_ws, size_t ws_size,
                              hipStream_t stream) {
  (void)in_sizes; (void)n_in; (void)out_size; (void)ws_size;
  const float* masks   = (const float*)d_in[0];
  const int*   n_ids   = (const int*)d_in[1];
  const int*   e0_src  = (const int*)d_in[2];
  const int*   e1_src  = (const int*)d_in[4];
  const float* pre_W   = (const float*)d_in[6];
  const float* pre_b   = (const float*)d_in[7];
  const float* gat_W   = (const float*)d_in[8];
  const float* gat_att = (const float*)d_in[9];
  const float* gat_b   = (const float*)d_in[10];
  const float* sp      = (const float*)d_in[11];
  const float* emb_W   = (const float*)d_in[12];
  const float* emb_b   = (const float*)d_in[13];

  float* out = (float*)d_out;
  float* dot = out;                         // [4096*4096]
  float* emb = out + (size_t)NB*NB;         // [4096*128]
  float* scales_out = emb + (size_t)NB*128; // [3]

  char* p = (char*)d_ws;
  auto alloc = [&](size_t bytes)->char*{ char* r = p; p += (bytes + 255) & ~(size_t)255; return r; };
  ushort_t* GT    = (ushort_t*)alloc((size_t)NM*PADC*HD*2);
  float*    alphG = (float*)alloc((size_t)NM*IN_SZ*4*4);
  uint32_t* g0u   = (uint32_t*)alloc((size_t)NM*N1*HD*2);
  ushort_t* xl1hi = (ushort_t*)alloc((size_t)NM*N1*HD*2);
  float*    alph1 = (float*)alloc((size_t)NM*N1*4*4);
  float*    xmod  = (float*)alloc((size_t)NB*HD*4);
  float*    coef  = (float*)alloc((size_t)NB*3*4);
  float*    wT    = (float*)alloc((size_t)HD*128*4);
  ushort_t* gWhi  = (ushort_t*)alloc((size_t)NM*HD*HD*2);
  ushort_t* gWlo  = (ushort_t*)alloc((size_t)NM*HD*HD*2);
  float*    bsum  = (float*)alloc((size_t)NM*HD*4);
  float*    batt  = (float*)alloc((size_t)NM*4*4);
  ushort_t* ehi   = (ushort_t*)alloc((size_t)NB*128*2);
  ushort_t* elo   = (ushort_t*)alloc((size_t)NB*128*2);

  prep_k<<<915, 256, 0, stream>>>(masks, sp, coef, scales_out, emb_W, wT,
                                  gat_W, gWhi, gWlo, pre_b, gat_att, gat_b, bsum, batt);
  gt_fused<<<dim3(PADC/128, 1, NM), 256, 0, stream>>>(
      pre_W, gWhi, gat_att, batt, GT, alphG);
  gat_msg0<<<dim3(N1, NM), 128, 0, stream>>>(GT, alphG, n_ids, e0_src, bsum, g0u);
  gemm2<<<dim3(2, N1/128, NM), 256, 0, stream>>>(
      (const ushort_t*)g0u, (size_t)N1*HD, gWhi, gWlo,
      xl1hi, (size_t)N1*HD, gat_att, alph1, (size_t)N1*4);
  gat_msg1<<<NB, 128, 0, stream>>>(xl1hi, alph1, e1_src, gat_b, g0u, coef, xmod);
  emb_gemm<<<NB/32, 256, 0, stream>>>(xmod, wT, emb_b, emb, ehi, elo);
  dot_mfma<<<dim3(32,32), 256, 0, stream>>>(ehi, elo, dot);
}

// Round 22
// 236.107 us; speedup vs baseline: 1.1382x; 1.0094x over previous
//
#include <hip/hip_runtime.h>
#include <hip/hip_bf16.h>
#include <cstdint>

#define IN_SZ 50000
#define PADC  50048
#define NM 3
#define N0 40960
#define N1 16384
#define NB 4096
#define HD 256
#define DEG 16
#define E0 (N1*DEG)
#define E1 (NB*DEG)

using short8v = __attribute__((ext_vector_type(8))) short;
using floatx4 = __attribute__((ext_vector_type(4))) float;
typedef unsigned short ushort_t;

__device__ __forceinline__ ushort_t f2bf(float f){
  uint32_t u = __float_as_uint(f);
  uint32_t r = u + 0x7FFFu + ((u>>16)&1u);
  return (ushort_t)(r>>16);
}
__device__ __forceinline__ float bf2f(ushort_t h){
  return __uint_as_float(((uint32_t)h)<<16);
}
__device__ __forceinline__ void gload_lds16(const void* g, void* l){
  __builtin_amdgcn_global_load_lds(
      (const __attribute__((address_space(1))) void*)g,
      (__attribute__((address_space(3))) void*)l, 16, 0, 0);
}

// ---------------- threefry2x32 (JAX-exact) ----------------
__device__ __forceinline__ uint32_t rotl32(uint32_t x, uint32_t d){ return (x<<d)|(x>>(32u-d)); }

__device__ void tf2x32(uint32_t k0, uint32_t k1, uint32_t c0, uint32_t c1,
                       uint32_t& y0, uint32_t& y1)
{
  uint32_t ks2 = k0 ^ k1 ^ 0x1BD11BDAu;
  uint32_t x0 = c0 + k0, x1 = c1 + k1;
#define R4(a,b,c,d) \
  x0+=x1; x1=rotl32(x1,a); x1^=x0; \
  x0+=x1; x1=rotl32(x1,b); x1^=x0; \
  x0+=x1; x1=rotl32(x1,c); x1^=x0; \
  x0+=x1; x1=rotl32(x1,d); x1^=x0;
  R4(13,15,26,6)  x0+=k1;  x1+=ks2+1u;
  R4(17,29,16,24) x0+=ks2; x1+=k0+2u;
  R4(13,15,26,6)  x0+=k0;  x1+=k1+3u;
  R4(17,29,16,24) x0+=k1;  x1+=ks2+4u;
  R4(13,15,26,6)  x0+=ks2; x1+=k0+5u;
#undef R4
  y0=x0; y1=x1;
}

// ---- merged prep: [0,16) interp | [16,144) embW transpose | [144,912) split | [912,915) bias ----
__global__ __launch_bounds__(256) void prep_k(
    const float* __restrict__ masks, const float* __restrict__ sp,
    float* __restrict__ coef, float* __restrict__ scales_out,
    const float* __restrict__ emb_W, float* __restrict__ wT,
    const float* __restrict__ gat_W, ushort_t* __restrict__ gWhi, ushort_t* __restrict__ gWlo,
    const float* __restrict__ pre_b, const float* __restrict__ gat_att,
    const float* __restrict__ gat_b, float* __restrict__ bsum, float* __restrict__ batt)
{
  int blk = blockIdx.x;
  int t = threadIdx.x;
  if (blk < 16){
    int b = blk*256 + t;
    float s0=sp[0], s1=sp[1], s2=sp[2];
    float mx = fmaxf(s0,fmaxf(s1,s2));
    float e0=expf(s0-mx), e1=expf(s1-mx), e2=expf(s2-mx);
    float inv = 1.f/(e0+e1+e2);
    float sc[3] = {e0*inv, e1*inv, e2*inv};
    if (b == 0){ scales_out[0]=sc[0]; scales_out[1]=sc[1]; scales_out[2]=sc[2]; }
    uint32_t bits[3];
    uint32_t K0,K1, t0,t1;
    tf2x32(0u,42u,0u,1u,K0,K1);
    for (int i=0;i<3;i++){
      uint32_t idx = (uint32_t)(b*3+i);
      tf2x32(K0,K1,0u,idx,t0,t1);
      bits[i] = (t0 ^ t1) & 1u;
    }
    float mk[3] = {masks[b*3+0], masks[b*3+1], masks[b*3+2]};
    float msum = mk[0]+mk[1]+mk[2];
    float rs = (float)(bits[0]+bits[1]+bits[2]);
    float add = powf(1.f/(1.f+rs), 20.f) + powf(1.f/msum, 20.f);
    float lg[3]; float lmax = -1e30f;
    for (int i=0;i<3;i++){
      float rm = floorf((float)bits[i] + add);
      rm = rm/(rm+1e-10f);
      float mm = mk[i]*rm;
      lg[i] = mm + (1.f-mm)*(-1e10f);
      lmax = fmaxf(lmax, lg[i]);
    }
    float es[3], ssum=0.f;
    for (int i=0;i<3;i++){ es[i]=expf(lg[i]-lmax); ssum+=es[i]; }
    for (int i=0;i<3;i++) coef[b*3+i] = sc[i]*es[i]/ssum;
  } else if (blk < 144){
    int g = (blk-16)*256 + t;
    int j = g >> 8, k = g & 255;
    wT[k*128 + j] = emb_W[g];
  } else if (blk < 912){
    int g = (blk-144)*256 + t;
    float v = gat_W[g];
    ushort_t h = f2bf(v);
    gWhi[g] = h;
    gWlo[g] = f2bf(v - bf2f(h));
  } else {
    int i = blk - 912, o = t;
    const float* W = gat_W + (size_t)i*HD*HD + (size_t)o*HD;
    const float* b = pre_b + i*HD;
    float s = 0.f;
    for (int k=0;k<HD;k++) s = fmaf(b[k], W[k], s);
    bsum[i*HD + o] = s + gat_b[i*HD + o];
    __shared__ float red[256];
    red[o] = s * gat_att[i*HD + o];
    __syncthreads();
    if (o < 4){
      float p = 0.f;
      for (int j=0;j<64;j++) p += red[o*64 + j];
      batt[i*4 + o] = p;
    }
  }
}

// ---- fused transpose + GT GEMM v4: 512 threads (8 waves), counted-vmcnt pipeline ----
// GT[c,o] = sum_k preW[k,c]*gatW_hi[o,k]. A: fp32 [32k x 128c] chunks DMA'd with
// source-quad swizzle; transposed at ds_read time. Per chunk: issue next (4 DMA),
// s_waitcnt vmcnt(4), raw s_barrier, compute, end s_barrier. Each wave owns one
// 16-row tile. Same 64KB LDS -> 2 blk/CU but 16 waves/CU (2x TLP vs v3).
__global__ __launch_bounds__(512) void gt_fused(
    const float* __restrict__ preW_b,
    const ushort_t* __restrict__ Whi_b,
    const float* __restrict__ att_b, const float* __restrict__ batt,
    ushort_t* __restrict__ GT_b, float* __restrict__ alphaG_b)
{
  int i = blockIdx.z;
  int brow = blockIdx.x * 128;
  const float* pw = preW_b + (size_t)i*HD*IN_SZ;
  const ushort_t* Whi = Whi_b + (size_t)i*HD*HD;
  const float* att = att_b + (size_t)i*HD;
  ushort_t* GT = GT_b + (size_t)i*(size_t)PADC*HD;
  float* alphaG = alphaG_b + (size_t)i*IN_SZ*4;

  __shared__ __align__(16) float    As[2][32*128];   // 16 KB x2
  __shared__ __align__(16) ushort_t Bs[2][16*512];   // 16 KB x2  (64 KB total)
  int t = threadIdx.x, wave = t>>6, lane = t&63;
  int l15 = lane&15, kq = lane>>4;

  int aRow[2]; int aCol[2];
#pragma unroll
  for (int r=0;r<2;r++){
    int lin = r*512 + t;
    aRow[r] = lin >> 5;
    int colq = lin & 31;
    int srcc = brow + ((colq ^ (((aRow[r]>>3)&3)<<2)) << 2);
    if (srcc > IN_SZ-4) srcc = IN_SZ-4;
    aCol[r] = srcc;
  }
  const ushort_t* bSrc[2];
#pragma unroll
  for (int r=0;r<2;r++){
    int f = wave + r*8;
    bSrc[r] = Whi + (size_t)(f*16 + l15)*HD + kq*8;
  }

  floatx4 acc[16];
#pragma unroll
  for (int ot=0;ot<16;ot++) acc[ot] = (floatx4){0.f,0.f,0.f,0.f};

  // transposed-read col index for this wave's row-tile rt = wave
  int clds = (((wave*4 + (l15>>2)) ^ (kq<<2)) << 2) + (l15 & 3);

  // 4 DMA instructions per thread per chunk, program-ordered
  auto issue = [&](int cc, int bufi){
    int k0 = cc*32;
#pragma unroll
    for (int r=0;r<2;r++)
      gload_lds16(pw + (size_t)(k0 + aRow[r])*IN_SZ + aCol[r],
                  &As[bufi][(r*512 + wave*64)*4] + lane*4);
#pragma unroll
    for (int r=0;r<2;r++)
      gload_lds16(bSrc[r] + k0, &Bs[bufi][(wave + r*8)*512] + lane*8);
  };

  issue(0, 0);   // prologue

  for (int cc=0; cc<8; cc++){
    int buf = cc & 1;
    if (cc < 7) issue(cc + 1, buf ^ 1);   // prefetch; stays in flight across barrier
    if (cc < 7) asm volatile("s_waitcnt vmcnt(4)" ::: "memory");
    else        asm volatile("s_waitcnt vmcnt(0)" ::: "memory");
    __builtin_amdgcn_sched_barrier(0);
    __builtin_amdgcn_s_barrier();          // all waves' chunk-cc data in LDS
    __builtin_amdgcn_sched_barrier(0);

    short8v a;
    {
      float af[8];
#pragma unroll
      for (int j=0;j<8;j++) af[j] = As[buf][(kq*8+j)*128 + clds];
      union { uint32_t u[4]; short8v v; } cv;
#pragma unroll
      for (int j=0;j<4;j++)
        asm("v_cvt_pk_bf16_f32 %0, %1, %2" : "=v"(cv.u[j]) : "v"(af[2*j]), "v"(af[2*j+1]));
      a = cv.v;
    }
#pragma unroll
    for (int ot=0;ot<16;ot++){
      short8v bh = *reinterpret_cast<const short8v*>(&Bs[buf][ot*512 + lane*8]);
      acc[ot] = __builtin_amdgcn_mfma_f32_16x16x32_bf16(a, bh, acc[ot], 0,0,0);
    }
    __builtin_amdgcn_sched_barrier(0);
    __builtin_amdgcn_s_barrier();          // reads of buf done -> next issue may overwrite
  }

  // epilogue
  float attv[16];
#pragma unroll
  for (int ot=0;ot<16;ot++) attv[ot] = att[ot*16 + l15];
  int rbase = brow + wave*16 + kq*4;
#pragma unroll
  for (int jj=0;jj<4;jj++){
    int c = rbase + jj;
    bool ok = c < IN_SZ;
    size_t rw = (size_t)c*HD;
    if (ok){
#pragma unroll
      for (int ot=0;ot<16;ot++) GT[rw + ot*16 + l15] = f2bf(acc[ot][jj]);
    }
#pragma unroll
    for (int h=0;h<4;h++){
      float p = acc[4*h+0][jj]*attv[4*h+0] + acc[4*h+1][jj]*attv[4*h+1]
              + acc[4*h+2][jj]*attv[4*h+2] + acc[4*h+3][jj]*attv[4*h+3];
      p += __shfl_xor(p, 1, 64);
      p += __shfl_xor(p, 2, 64);
      p += __shfl_xor(p, 4, 64);
      p += __shfl_xor(p, 8, 64);
      if (l15 == 0 && ok){
        p += batt[i*4 + h];
        alphaG[(size_t)c*4 + h] = p > 0.f ? p : 0.2f*p;
      }
    }
  }
}

// ---- MFMA GEMM (layer 1): 128x128 tile, DMA-staged, 2-term ----
__global__ __launch_bounds__(256) void gemm2(
    const ushort_t* __restrict__ A_b, size_t a_stride,
    const ushort_t* __restrict__ Whi_b, const ushort_t* __restrict__ Wlo_b,
    ushort_t* __restrict__ C_b, size_t c_stride,
    const float* __restrict__ att_b, float* __restrict__ alpha_b, size_t al_stride)
{
  int i = blockIdx.z;
  int bn0 = blockIdx.x * 128;
  int brow = blockIdx.y * 128;
  const ushort_t* A = A_b + (size_t)i*a_stride;
  const ushort_t* Whi = Whi_b + (size_t)i*HD*HD;
  const ushort_t* Wlo = Wlo_b + (size_t)i*HD*HD;
  ushort_t* C = C_b + (size_t)i*c_stride;
  const float* att = att_b + (size_t)i*HD;
  float* alpha = alpha_b + (size_t)i*al_stride;

  __shared__ __align__(16) ushort_t smem[2][24*512];
  int t = threadIdx.x, wave = t>>6, lane = t&63;
  int l15 = lane&15, kq = lane>>4;

  int row0 = brow + wave*16 + l15;
  int row1 = brow + (wave+4)*16 + l15;

  const ushort_t* gsrc[6];
  gsrc[0] = A + (size_t)row0*HD + kq*8;
  gsrc[1] = A + (size_t)row1*HD + kq*8;
#pragma unroll
  for (int j=2;j<6;j++){
    int idx = wave + 4*(j-2);
    int ct = idx>>1, h = idx&1;
    const ushort_t* W = h ? Wlo : Whi;
    gsrc[j] = W + (size_t)(bn0 + ct*16 + l15)*HD + kq*8;
  }

  floatx4 acc[4][4];
#pragma unroll
  for (int r=0;r<4;r++)
#pragma unroll
    for (int c=0;c<4;c++) acc[r][c] = (floatx4){0.f,0.f,0.f,0.f};

  int wm = wave>>1, wn = wave&1;

#pragma unroll
  for (int j=0;j<6;j++)
    gload_lds16(gsrc[j], &smem[0][(wave + 4*j)*512] + lane*8);
  __syncthreads();

  for (int cc=0; cc<8; cc++){
    int buf = cc & 1;
    if (cc < 7){
      int k0 = (cc+1)*32;
#pragma unroll
      for (int j=0;j<6;j++)
        gload_lds16(gsrc[j] + k0, &smem[buf^1][(wave + 4*j)*512] + lane*8);
    }
    short8v a[4];
#pragma unroll
    for (int r=0;r<4;r++)
      a[r] = *reinterpret_cast<const short8v*>(&smem[buf][(wm*4+r)*512 + lane*8]);
#pragma unroll
    for (int c=0;c<4;c++){
      int ct = wn*4+c;
      short8v bh = *reinterpret_cast<const short8v*>(&smem[buf][(8+ct*2)*512 + lane*8]);
      short8v bl = *reinterpret_cast<const short8v*>(&smem[buf][(9+ct*2)*512 + lane*8]);
#pragma unroll
      for (int r=0;r<4;r++){
        acc[r][c] = __builtin_amdgcn_mfma_f32_16x16x32_bf16(a[r], bh, acc[r][c], 0,0,0);
        acc[r][c] = __builtin_amdgcn_mfma_f32_16x16x32_bf16(a[r], bl, acc[r][c], 0,0,0);
      }
    }
    __syncthreads();
  }

  float attv[4];
#pragma unroll
  for (int c=0;c<4;c++) attv[c] = att[bn0 + (wn*4+c)*16 + l15];
  int head = (bn0>>6) + wn;
#pragma unroll
  for (int r=0;r<4;r++){
    int rowb = brow + wm*64 + r*16 + kq*4;
#pragma unroll
    for (int j=0;j<4;j++){
      size_t rw = (size_t)(rowb + j)*HD;
#pragma unroll
      for (int c=0;c<4;c++)
        C[rw + bn0 + (wn*4+c)*16 + l15] = f2bf(acc[r][c][j]);
    }
#pragma unroll
    for (int j=0;j<4;j++){
      float p = acc[r][0][j]*attv[0] + acc[r][1][j]*attv[1]
              + acc[r][2][j]*attv[2] + acc[r][3][j]*attv[3];
      p += __shfl_xor(p, 1, 64);
      p += __shfl_xor(p, 2, 64);
      p += __shfl_xor(p, 4, 64);
      p += __shfl_xor(p, 8, 64);
      if (l15 == 0){
        float lg = p > 0.f ? p : 0.2f*p;
        alpha[(size_t)(rowb + j)*4 + head] = lg;
      }
    }
  }
}

// ---- layer-0 GAT message: gathers GT rows via n_ids-remapped sources ----
__global__ __launch_bounds__(128) void gat_msg0(
    const ushort_t* __restrict__ GT_b, const float* __restrict__ alphaG_b,
    const int* __restrict__ n_ids, const int* __restrict__ esrc_b,
    const float* __restrict__ bsum_b, uint32_t* __restrict__ g0_u)
{
  int i = blockIdx.y, d = blockIdx.x, t = threadIdx.x;
  const ushort_t* GT = GT_b + (size_t)i*(size_t)PADC*HD;
  const float* alphaG = alphaG_b + (size_t)i*IN_SZ*4;
  const float* bsum = bsum_b + i*HD;
  __shared__ int src[16];
  __shared__ float aw[16][4];
  if (t < 16) src[t] = n_ids[(size_t)i*N0 + esrc_b[(size_t)i*E0 + d*16 + t]];
  __syncthreads();
  if (t < 64){
    int e = t&15, h = t>>4;
    float l = alphaG[(size_t)src[e]*4 + h];
    float m = l;
#pragma unroll
    for (int off=1; off<16; off<<=1) m = fmaxf(m, __shfl_xor(m, off, 64));
    float ex = expf(l - m);
    float s = ex;
#pragma unroll
    for (int off=1; off<16; off<<=1) s += __shfl_xor(s, off, 64);
    aw[e][h] = ex / (s + 1e-16f);
  }
  __syncthreads();
  int h = t >> 5;
  float a0=0.f, a1=0.f;
#pragma unroll
  for (int e=0;e<16;e++){
    uint32_t u = *reinterpret_cast<const uint32_t*>(GT + (size_t)src[e]*HD + 2*t);
    float w = aw[e][h];
    a0 = fmaf(w, bf2f((ushort_t)(u & 0xffffu)), a0);
    a1 = fmaf(w, bf2f((ushort_t)(u >> 16)), a1);
  }
  float v0 = a0 + bsum[2*t], v1 = a1 + bsum[2*t+1];
  g0_u[((size_t)i*N1 + d)*128 + t] = (uint32_t)f2bf(v0) | ((uint32_t)f2bf(v1)<<16);
}

// ---- layer-1 GAT message: fused gate + accumulate over modalities -> xmod fp32 ----
__global__ __launch_bounds__(128) void gat_msg1(
    const ushort_t* __restrict__ xl1hi, const float* __restrict__ alpha1,
    const int* __restrict__ e1src, const float* __restrict__ gat_b,
    const uint32_t* __restrict__ g0_u, const float* __restrict__ coef,
    float* __restrict__ xmod)
{
  int d = blockIdx.x, t = threadIdx.x;
  __shared__ int src[16];
  __shared__ float aw[16][4];
  float o0 = 0.f, o1 = 0.f;
  for (int i=0;i<NM;i++){
    if (t < 16) src[t] = e1src[(size_t)i*E1 + d*16 + t];
    __syncthreads();
    if (t < 64){
      int e = t&15, h = t>>4;
      float l = alpha1[((size_t)i*N1 + src[e])*4 + h];
      float m = l;
#pragma unroll
      for (int off=1; off<16; off<<=1) m = fmaxf(m, __shfl_xor(m, off, 64));
      float ex = expf(l - m);
      float s = ex;
#pragma unroll
      for (int off=1; off<16; off<<=1) s += __shfl_xor(s, off, 64);
      aw[e][h] = ex / (s + 1e-16f);
    }
    __syncthreads();
    const ushort_t* xl = xl1hi + (size_t)i*N1*HD;
    int h = t >> 5;
    float a0=0.f, a1=0.f;
#pragma unroll
    for (int e=0;e<16;e++){
      uint32_t u = *reinterpret_cast<const uint32_t*>(xl + (size_t)src[e]*HD + 2*t);
      float w = aw[e][h];
      a0 = fmaf(w, bf2f((ushort_t)(u & 0xffffu)), a0);
      a1 = fmaf(w, bf2f((ushort_t)(u >> 16)), a1);
    }
    uint32_t gh = g0_u[((size_t)i*N1 + d)*128 + t];
    float g00 = bf2f((ushort_t)(gh & 0xffffu));
    float g01 = bf2f((ushort_t)(gh >> 16));
    const float* bias = gat_b + i*HD;
    float cv = coef[d*3 + i];
    o0 += cv*(2.f*g00 + 2.f*(a0 + bias[2*t]));
    o1 += cv*(2.f*g01 + 2.f*(a1 + bias[2*t+1]));
    __syncthreads();
  }
  *reinterpret_cast<float2*>(&xmod[(size_t)d*HD + 2*t]) = make_float2(o0, o1);
}

// ---- emb = xmod @ embW^T + b; writes fp32 + hi/lo bf16 ----
__global__ __launch_bounds__(256) void emb_gemm(
  const float* __restrict__ xmod, const float* __restrict__ wT,
  const float* __restrict__ eb, float* __restrict__ emb,
  ushort_t* __restrict__ ehi, ushort_t* __restrict__ elo)
{
  __shared__ float xs[32][260];
  int t = threadIdx.x;
  int brow = blockIdx.x * 32;
#pragma unroll
  for (int j=0;j<8;j++){
    int linear = j*256+t;
    int row = linear >> 6;
    int kq = linear & 63;
    float4 f = *reinterpret_cast<const float4*>(&xmod[(size_t)(brow+row)*256 + kq*4]);
    xs[row][kq*4+0]=f.x; xs[row][kq*4+1]=f.y; xs[row][kq*4+2]=f.z; xs[row][kq*4+3]=f.w;
  }
  __syncthreads();
  int tj = t & 127, th = t >> 7;
  float acc[16];
#pragma unroll
  for(int r=0;r<16;r++) acc[r]=0.f;
  for (int k=0;k<256;k++){
    float w = wT[k*128 + tj];
#pragma unroll
    for (int r=0;r<16;r++) acc[r] = fmaf(xs[th*16+r][k], w, acc[r]);
  }
  float bias = eb[tj];
#pragma unroll
  for (int r=0;r<16;r++){
    size_t idx = (size_t)(brow+th*16+r)*128 + tj;
    float v = acc[r] + bias;
    emb[idx] = v;
    ushort_t hb = f2bf(v);
    ehi[idx] = hb;
    elo[idx] = f2bf(v - bf2f(hb));
  }
}

// ---- dot = emb @ emb^T via MFMA, 3-term split ----
__global__ __launch_bounds__(256) void dot_mfma(
    const ushort_t* __restrict__ Ehi, const ushort_t* __restrict__ Elo,
    float* __restrict__ dot)
{
  __shared__ __align__(16) ushort_t lb[2][16384];
  int t = threadIdx.x, wave = t>>6, lane = t&63;
  int arow0 = blockIdx.y*128, brow0 = blockIdx.x*128;
  {
    const ushort_t* srcp = (t<128) ? Ehi : Elo;
    ushort_t* dstb = lb[(t<128)?0:1];
    int o = t & 127;
    const ushort_t* rp = srcp + (size_t)(brow0+o)*128;
#pragma unroll
    for (int g=0; g<16; g++){
      short8v v = *reinterpret_cast<const short8v*>(rp + g*8);
      int c = g>>2, grp = g&3;
      int lidx = c*4096 + (o>>4)*512 + ((grp<<4)|(o&15))*8;
      *reinterpret_cast<short8v*>(&dstb[lidx]) = v;
    }
  }
  __syncthreads();

  floatx4 acc[2][8];
#pragma unroll
  for (int rt=0;rt<2;rt++)
#pragma unroll
    for (int ot=0;ot<8;ot++) acc[rt][ot] = (floatx4){0.f,0.f,0.f,0.f};

  int ar0 = arow0 + wave*32 + (lane&15);
  int ar1 = ar0 + 16;
  int koff = (lane>>4)*8;
#pragma unroll
  for (int c=0;c<4;c++){
    short8v ah0 = *reinterpret_cast<const short8v*>(Ehi + (size_t)ar0*128 + c*32 + koff);
    short8v ah1 = *reinterpret_cast<const short8v*>(Ehi + (size_t)ar1*128 + c*32 + koff);
    short8v al0 = *reinterpret_cast<const short8v*>(Elo + (size_t)ar0*128 + c*32 + koff);
    short8v al1 = *reinterpret_cast<const short8v*>(Elo + (size_t)ar1*128 + c*32 + koff);
#pragma unroll
    for (int ot=0;ot<8;ot++){
      short8v bh = *reinterpret_cast<const short8v*>(&lb[0][c*4096 + ot*512 + lane*8]);
      short8v bl = *reinterpret_cast<const short8v*>(&lb[1][c*4096 + ot*512 + lane*8]);
      acc[0][ot] = __builtin_amdgcn_mfma_f32_16x16x32_bf16(ah0, bh, acc[0][ot], 0,0,0);
      acc[0][ot] = __builtin_amdgcn_mfma_f32_16x16x32_bf16(ah0, bl, acc[0][ot], 0,0,0);
      acc[0][ot] = __builtin_amdgcn_mfma_f32_16x16x32_bf16(al0, bh, acc[0][ot], 0,0,0);
      acc[1][ot] = __builtin_amdgcn_mfma_f32_16x16x32_bf16(ah1, bh, acc[1][ot], 0,0,0);
      acc[1][ot] = __builtin_amdgcn_mfma_f32_16x16x32_bf16(ah1, bl, acc[1][ot], 0,0,0);
      acc[1][ot] = __builtin_amdgcn_mfma_f32_16x16x32_bf16(al1, bh, acc[1][ot], 0,0,0);
    }
  }
#pragma unroll
  for (int rt=0;rt<2;rt++){
    int rb = arow0 + wave*32 + rt*16 + (lane>>4)*4;
#pragma unroll
    for (int r=0;r<4;r++)
#pragma unroll
      for (int ot=0;ot<8;ot++)
        dot[(size_t)(rb+r)*4096 + brow0 + ot*16 + (lane&15)] = acc[rt][ot][r];
  }
}

extern "C" void kernel_launch(void* const* d_in, const int* in_sizes, int n_in,
                              void* d_out, int out_size, void* d_ws, size_t ws_size,
                              hipStream_t stream) {
  (void)in_sizes; (void)n_in; (void)out_size; (void)ws_size;
  const float* masks   = (const float*)d_in[0];
  const int*   n_ids   = (const int*)d_in[1];
  const int*   e0_src  = (const int*)d_in[2];
  const int*   e1_src  = (const int*)d_in[4];
  const float* pre_W   = (const float*)d_in[6];
  const float* pre_b   = (const float*)d_in[7];
  const float* gat_W   = (const float*)d_in[8];
  const float* gat_att = (const float*)d_in[9];
  const float* gat_b   = (const float*)d_in[10];
  const float* sp      = (const float*)d_in[11];
  const float* emb_W   = (const float*)d_in[12];
  const float* emb_b   = (const float*)d_in[13];

  float* out = (float*)d_out;
  float* dot = out;                         // [4096*4096]
  float* emb = out + (size_t)NB*NB;         // [4096*128]
  float* scales_out = emb + (size_t)NB*128; // [3]

  char* p = (char*)d_ws;
  auto alloc = [&](size_t bytes)->char*{ char* r = p; p += (bytes + 255) & ~(size_t)255; return r; };
  ushort_t* GT    = (ushort_t*)alloc((size_t)NM*PADC*HD*2);
  float*    alphG = (float*)alloc((size_t)NM*IN_SZ*4*4);
  uint32_t* g0u   = (uint32_t*)alloc((size_t)NM*N1*HD*2);
  ushort_t* xl1hi = (ushort_t*)alloc((size_t)NM*N1*HD*2);
  float*    alph1 = (float*)alloc((size_t)NM*N1*4*4);
  float*    xmod  = (float*)alloc((size_t)NB*HD*4);
  float*    coef  = (float*)alloc((size_t)NB*3*4);
  float*    wT    = (float*)alloc((size_t)HD*128*4);
  ushort_t* gWhi  = (ushort_t*)alloc((size_t)NM*HD*HD*2);
  ushort_t* gWlo  = (ushort_t*)alloc((size_t)NM*HD*HD*2);
  float*    bsum  = (float*)alloc((size_t)NM*HD*4);
  float*    batt  = (float*)alloc((size_t)NM*4*4);
  ushort_t* ehi   = (ushort_t*)alloc((size_t)NB*128*2);
  ushort_t* elo   = (ushort_t*)alloc((size_t)NB*128*2);

  prep_k<<<915, 256, 0, stream>>>(masks, sp, coef, scales_out, emb_W, wT,
                                  gat_W, gWhi, gWlo, pre_b, gat_att, gat_b, bsum, batt);
  gt_fused<<<dim3(PADC/128, 1, NM), 512, 0, stream>>>(
      pre_W, gWhi, gat_att, batt, GT, alphG);
  gat_msg0<<<dim3(N1, NM), 128, 0, stream>>>(GT, alphG, n_ids, e0_src, bsum, g0u);
  gemm2<<<dim3(2, N1/128, NM), 256, 0, stream>>>(
      (const ushort_t*)g0u, (size_t)N1*HD, gWhi, gWlo,
      xl1hi, (size_t)N1*HD, gat_att, alph1, (size_t)N1*4);
  gat_msg1<<<NB, 128, 0, stream>>>(xl1hi, alph1, e1_src, gat_b, g0u, coef, xmod);
  emb_gemm<<<NB/32, 256, 0, stream>>>(xmod, wT, emb_b, emb, ehi, elo);
  dot_mfma<<<dim3(32,32), 256, 0, stream>>>(ehi, elo, dot);
}